// Round 1
// baseline (16494.743 us; speedup 1.0000x reference)
//
#include <hip/hip_runtime.h>
#include <stdint.h>

// GP posterior via batched CG:  Z = Khat^{-1} Kxs,  mean = Z^T y,
// var = s + sn - coldot(Kxs, Z).  Khat stored bf16 (128 MB), solve = 12 CG
// iterations whose cost is one bf16 MFMA GEMM (M=4096,N=8192,K=8192) each.

#define N_TRAIN 8192
#define N_TEST  4096
#define DIM     16
#define KDIM    8192
#define CG_ITERS 12

using f32x4  = __attribute__((ext_vector_type(4))) float;
using bf16x8 = __attribute__((ext_vector_type(8))) short;

__device__ __forceinline__ unsigned short f2bf(float f) {
  unsigned u = __float_as_uint(f);
  u = (u + 0x7FFFu + ((u >> 16) & 1u)) >> 16;   // round-to-nearest-even
  return (unsigned short)u;
}
__device__ __forceinline__ float bf2f(unsigned short h) {
  return __uint_as_float(((unsigned)h) << 16);
}

__device__ __forceinline__ void gl_lds16(const void* g, void* l) {
  __builtin_amdgcn_global_load_lds(
      (const __attribute__((address_space(1))) unsigned int*)g,
      (__attribute__((address_space(3))) unsigned int*)l, 16, 0, 0);
}

__device__ __forceinline__ float block_reduce_sum(float v, float* sbuf) {
  #pragma unroll
  for (int off = 32; off > 0; off >>= 1) v += __shfl_down(v, off, 64);
  int lane = threadIdx.x & 63, w = threadIdx.x >> 6;
  __syncthreads();                    // protect sbuf against prior use
  if (lane == 0) sbuf[w] = v;
  __syncthreads();
  return sbuf[0] + sbuf[1] + sbuf[2] + sbuf[3];
}

// ---- prep: rows scaled by 1/lengthscale + squared norms ----
__global__ void prep_kernel(const float* __restrict__ tx, const float* __restrict__ xx,
                            const float* __restrict__ ls,
                            float* __restrict__ As, float* __restrict__ an,
                            float* __restrict__ Bs, float* __restrict__ bn) {
  int i = blockIdx.x * 256 + threadIdx.x;
  if (i < N_TRAIN) {
    float s = 0.f;
    #pragma unroll
    for (int d = 0; d < DIM; ++d) {
      float v = tx[(size_t)i * DIM + d] / ls[d];
      As[(size_t)i * DIM + d] = v; s += v * v;
    }
    an[i] = s;
  } else if (i < N_TRAIN + N_TEST) {
    int j = i - N_TRAIN;
    float s = 0.f;
    #pragma unroll
    for (int d = 0; d < DIM; ++d) {
      float v = xx[(size_t)j * DIM + d] / ls[d];
      Bs[(size_t)j * DIM + d] = v; s += v * v;
    }
    bn[j] = s;
  }
}

// ---- kernel-matrix tile builder: out[i][j] = s*exp(-0.5*d2) (+ sn on diag) ----
template <bool BF16OUT, bool ADDNOISE>
__global__ __launch_bounds__(256) void build_kernel(
    const float* __restrict__ RI, const float* __restrict__ nI,  // row side
    const float* __restrict__ RJ, const float* __restrict__ nJ,  // train side
    void* __restrict__ out, const float* __restrict__ osc, const float* __restrict__ noi)
{
  __shared__ float aI[128 * DIM];
  __shared__ float aJ[128 * DIM];
  __shared__ float sI[128], sJ[128];
  int t = threadIdx.x;
  int i0 = blockIdx.y * 128, j0 = blockIdx.x * 128;
  for (int e = t; e < 128 * DIM; e += 256) {
    aI[e] = RI[(size_t)i0 * DIM + e];
    aJ[e] = RJ[(size_t)j0 * DIM + e];
  }
  if (t < 128) sI[t] = nI[i0 + t];
  else         sJ[t - 128] = nJ[j0 + t - 128];
  __syncthreads();
  float s = osc[0], sn = noi[0];
  int r  = t >> 1;
  int ch = (t & 1) * 64;
  float ar[DIM];
  #pragma unroll
  for (int d = 0; d < DIM; ++d) ar[d] = aI[r * DIM + d];
  float nr = sI[r];
  unsigned short* o16 = (unsigned short*)out;
  float* o32 = (float*)out;
  for (int c = 0; c < 64; ++c) {
    int col = ch + c;
    float dot = 0.f;
    #pragma unroll
    for (int d = 0; d < DIM; ++d) dot += ar[d] * aJ[col * DIM + d];
    float d2 = fmaxf(nr + sJ[col] - 2.f * dot, 0.f);
    float v = s * __expf(-0.5f * d2);
    if (ADDNOISE && (i0 + r == j0 + col)) v += sn;
    size_t idx = (size_t)(i0 + r) * KDIM + (size_t)(j0 + col);
    if (BF16OUT) o16[idx] = f2bf(v); else o32[idx] = v;
  }
}

// ---- m97-structure bf16 GEMM:  C[M][8192] = A[M][8192] * B^T (B row-major [8192][8192]) ----
__global__ __launch_bounds__(256) void gemm_bt(
    const unsigned short* __restrict__ A,   // Pb  [M][KDIM] bf16
    const unsigned short* __restrict__ B,   // Khat [8192][KDIM] bf16 (symmetric)
    float* __restrict__ C)                   // Qt  [M][8192] f32
{
  __shared__ unsigned short Asm[128 * 64];
  __shared__ unsigned short Bsm[128 * 64];
  int tid = threadIdx.x;
  int lane = tid & 63, wave = tid >> 6;
  int wm = wave >> 1, wn = wave & 1;
  int bm = blockIdx.y * 128, bn = blockIdx.x * 128;

  const char* ga[4]; const char* gb[4];
  char* la[4]; char* lb[4];
  #pragma unroll
  for (int q = 0; q < 4; ++q) {
    int ob = (wave * 4 + q) * 1024 + lane * 16;   // linear byte offset in 16KB tile
    int r = ob >> 7, cb = ob & 127;               // 128B per row (64 bf16)
    ga[q] = (const char*)(A + (size_t)(bm + r) * KDIM) + cb;
    gb[q] = (const char*)(B + (size_t)(bn + r) * KDIM) + cb;
    la[q] = (char*)Asm + (wave * 4 + q) * 1024;   // wave-uniform LDS base
    lb[q] = (char*)Bsm + (wave * 4 + q) * 1024;
  }

  f32x4 acc[4][4] = {};

  for (int kt = 0; kt < KDIM; kt += 64) {
    #pragma unroll
    for (int q = 0; q < 4; ++q) {
      gl_lds16(ga[q], la[q]); ga[q] += 128;
      gl_lds16(gb[q], lb[q]); gb[q] += 128;
    }
    __syncthreads();
    #pragma unroll
    for (int ks = 0; ks < 2; ++ks) {
      bf16x8 af[4], bfr[4];
      int kc = ks * 32 + (lane >> 4) * 8;
      #pragma unroll
      for (int i = 0; i < 4; ++i) {
        af[i]  = *(const bf16x8*)&Asm[(wm * 64 + i * 16 + (lane & 15)) * 64 + kc];
        bfr[i] = *(const bf16x8*)&Bsm[(wn * 64 + i * 16 + (lane & 15)) * 64 + kc];
      }
      #pragma unroll
      for (int i = 0; i < 4; ++i)
        #pragma unroll
        for (int j = 0; j < 4; ++j)
          acc[i][j] = __builtin_amdgcn_mfma_f32_16x16x32_bf16(af[i], bfr[j], acc[i][j], 0, 0, 0);
    }
    __syncthreads();
  }

  // verified C/D mapping: col = lane&15, row = (lane>>4)*4 + reg
  #pragma unroll
  for (int i = 0; i < 4; ++i) {
    #pragma unroll
    for (int j = 0; j < 4; ++j) {
      int row = bm + wm * 64 + i * 16 + (lane >> 4) * 4;
      int col = bn + wn * 64 + j * 16 + (lane & 15);
      #pragma unroll
      for (int rg = 0; rg < 4; ++rg)
        C[(size_t)(row + rg) * KDIM + col] = acc[i][j][rg];
    }
  }
}

// ---- CG init: Z=0, R=rhs, P=bf16(rhs), rr = ||rhs||^2 per column ----
__global__ __launch_bounds__(256) void cg_init(
    const float* __restrict__ Kxs, float* __restrict__ Z, float* __restrict__ R,
    unsigned short* __restrict__ P, float* __restrict__ rr)
{
  __shared__ float sbuf[4];
  int c = blockIdx.x, t = threadIdx.x;
  size_t base = (size_t)c * KDIM;
  float acc = 0.f;
  #pragma unroll
  for (int k = 0; k < KDIM / 256; ++k) {
    int j = t + k * 256;
    float v = Kxs[base + j];
    Z[base + j] = 0.f;
    R[base + j] = v;
    P[base + j] = f2bf(v);
    acc += v * v;
  }
  float tot = block_reduce_sum(acc, sbuf);
  if (t == 0) rr[c] = tot;
}

// ---- one fused CG step (after Q = Khat * P) ----
__global__ __launch_bounds__(256) void cg_step(
    const float* __restrict__ Q, float* __restrict__ Z, float* __restrict__ R,
    unsigned short* __restrict__ P, float* __restrict__ rr)
{
  __shared__ float sbuf[4];
  int c = blockIdx.x, t = threadIdx.x;
  size_t base = (size_t)c * KDIM;
  float p[32], q[32], rv[32];
  float s1 = 0.f;
  #pragma unroll
  for (int k = 0; k < 32; ++k) {
    int j = t + k * 256;
    p[k] = bf2f(P[base + j]);
    q[k] = Q[base + j];
    s1 += p[k] * q[k];
  }
  float pAp = block_reduce_sum(s1, sbuf);
  float rr_old = rr[c];
  float alpha = rr_old / fmaxf(pAp, 1e-37f);
  float s2 = 0.f;
  #pragma unroll
  for (int k = 0; k < 32; ++k) {
    int j = t + k * 256;
    Z[base + j] += alpha * p[k];
    float r = R[base + j] - alpha * q[k];
    R[base + j] = r;
    rv[k] = r;
    s2 += r * r;
  }
  float rrn = block_reduce_sum(s2, sbuf);
  float beta = rrn / fmaxf(rr_old, 1e-37f);
  if (t == 0) rr[c] = rrn;
  #pragma unroll
  for (int k = 0; k < 32; ++k) {
    int j = t + k * 256;
    P[base + j] = f2bf(rv[k] + beta * p[k]);
  }
}

// ---- outputs: mean = Z.y ; var = s + sn - Kxs.Z ----
__global__ __launch_bounds__(256) void finalize_kernel(
    const float* __restrict__ Z, const float* __restrict__ Kxs,
    const float* __restrict__ y, const float* __restrict__ osc,
    const float* __restrict__ noi, float* __restrict__ out, int c0)
{
  __shared__ float sbuf[4];
  int c = blockIdx.x, t = threadIdx.x;
  size_t base = (size_t)c * KDIM;
  float sm = 0.f, sv = 0.f;
  #pragma unroll
  for (int k = 0; k < 32; ++k) {
    int j = t + k * 256;
    float z = Z[base + j];
    sm += z * y[j];
    sv += z * Kxs[base + j];
  }
  float mean = block_reduce_sum(sm, sbuf);
  float kz   = block_reduce_sum(sv, sbuf);
  if (t == 0) {
    out[c0 + c] = mean;
    out[N_TEST + c0 + c] = osc[0] + noi[0] - kz;
  }
}

extern "C" void kernel_launch(void* const* d_in, const int* in_sizes, int n_in,
                              void* d_out, int out_size, void* d_ws, size_t ws_size,
                              hipStream_t stream) {
  const float* tx = (const float*)d_in[0];
  const float* ty = (const float*)d_in[1];
  const float* xx = (const float*)d_in[2];
  const float* os = (const float*)d_in[3];
  const float* ls = (const float*)d_in[4];
  const float* ns = (const float*)d_in[5];
  float* out = (float*)d_out;
  (void)in_sizes; (void)n_in; (void)out_size;

  auto pad = [](size_t x) { return (x + 255) & ~(size_t)255; };
  size_t fixed = pad((size_t)N_TRAIN * N_TRAIN * 2)
               + pad((size_t)N_TRAIN * DIM * 4) + pad((size_t)N_TRAIN * 4)
               + pad((size_t)N_TEST * DIM * 4) + pad((size_t)N_TEST * 4);
  int C = 4096;   // test-column chunk (multiple of 128)
  while (C > 128) {
    size_t tot = fixed + pad((size_t)C * 4)
               + 4 * pad((size_t)C * KDIM * 4) + pad((size_t)C * KDIM * 2);
    if (tot <= ws_size) break;
    C >>= 1;
  }

  char* w = (char*)d_ws;
  auto alloc = [&](size_t bytes) { char* p = w; w += ((bytes + 255) & ~(size_t)255); return p; };
  unsigned short* Kb  = (unsigned short*)alloc((size_t)N_TRAIN * N_TRAIN * 2);
  float* As  = (float*)alloc((size_t)N_TRAIN * DIM * 4);
  float* an  = (float*)alloc((size_t)N_TRAIN * 4);
  float* Bs  = (float*)alloc((size_t)N_TEST * DIM * 4);
  float* bn  = (float*)alloc((size_t)N_TEST * 4);
  float* rr  = (float*)alloc((size_t)C * 4);
  float* Kxs = (float*)alloc((size_t)C * KDIM * 4);
  float* Z   = (float*)alloc((size_t)C * KDIM * 4);
  float* Rm  = (float*)alloc((size_t)C * KDIM * 4);
  float* Qt  = (float*)alloc((size_t)C * KDIM * 4);
  unsigned short* Pb = (unsigned short*)alloc((size_t)C * KDIM * 2);

  prep_kernel<<<48, 256, 0, stream>>>(tx, xx, ls, As, an, Bs, bn);

  dim3 gK(KDIM / 128, N_TRAIN / 128);
  build_kernel<true, true><<<gK, 256, 0, stream>>>(As, an, As, an, Kb, os, ns);

  for (int c0 = 0; c0 < N_TEST; c0 += C) {
    dim3 gX(KDIM / 128, C / 128);
    build_kernel<false, false><<<gX, 256, 0, stream>>>(
        Bs + (size_t)c0 * DIM, bn + c0, As, an, Kxs, os, ns);
    cg_init<<<C, 256, 0, stream>>>(Kxs, Z, Rm, Pb, rr);
    dim3 gG(KDIM / 128, C / 128);
    for (int it = 0; it < CG_ITERS; ++it) {
      gemm_bt<<<gG, 256, 0, stream>>>(Pb, Kb, Qt);
      cg_step<<<C, 256, 0, stream>>>(Qt, Z, Rm, Pb, rr);
    }
    finalize_kernel<<<C, 256, 0, stream>>>(Z, Kxs, ty, os, ns, out, c0);
  }
}

// Round 2
// 6237.475 us; speedup vs baseline: 2.6445x; 2.6445x over previous
//
#include <hip/hip_runtime.h>
#include <stdint.h>

// GP posterior via batched CG with scalar identities:
//   b = Kxs column;  x_k = CG_k(Khat, b)
//   mean_c = y^T x_k = sum_i alpha_i * yp_i   (yp = y^T p, scalar recurrence)
//   var_c  = s + sn - b^T x_k,  b^T x_k = sum_i alpha_i * rr_i
// No Z / Kxs / finalize buffers: per-column state = R,P,Q (bf16) = 48 KB.

#define N_TRAIN 8192
#define N_TEST  4096
#define DIM     16
#define KDIM    8192
#define CG_ITERS 8

using f32x4  = __attribute__((ext_vector_type(4))) float;
using bf16x8 = __attribute__((ext_vector_type(8))) short;

static __device__ __forceinline__ unsigned short f2bf(float f) {
  unsigned u = __float_as_uint(f);
  u = (u + 0x7FFFu + ((u >> 16) & 1u)) >> 16;   // round-to-nearest-even
  return (unsigned short)u;
}
static __device__ __forceinline__ float bf2f(unsigned short h) {
  return __uint_as_float(((unsigned)h) << 16);
}

__device__ __forceinline__ void gl_lds16(const void* g, void* l) {
  __builtin_amdgcn_global_load_lds(
      (const __attribute__((address_space(1))) unsigned int*)g,
      (__attribute__((address_space(3))) unsigned int*)l, 16, 0, 0);
}

// block-wide reduce of two floats (256 threads)
__device__ __forceinline__ void block_reduce2(float& a, float& b, float* sbuf) {
  #pragma unroll
  for (int off = 32; off > 0; off >>= 1) {
    a += __shfl_down(a, off);
    b += __shfl_down(b, off);
  }
  int lane = threadIdx.x & 63, w = threadIdx.x >> 6;
  __syncthreads();
  if (lane == 0) { sbuf[w * 2] = a; sbuf[w * 2 + 1] = b; }
  __syncthreads();
  a = sbuf[0] + sbuf[2] + sbuf[4] + sbuf[6];
  b = sbuf[1] + sbuf[3] + sbuf[5] + sbuf[7];
}

// ---- prep: rows scaled by 1/lengthscale + squared norms ----
__global__ void prep_kernel(const float* __restrict__ tx, const float* __restrict__ xx,
                            const float* __restrict__ ls,
                            float* __restrict__ As, float* __restrict__ an,
                            float* __restrict__ Bs, float* __restrict__ bn) {
  int i = blockIdx.x * 256 + threadIdx.x;
  if (i < N_TRAIN) {
    float s = 0.f;
    #pragma unroll
    for (int d = 0; d < DIM; ++d) {
      float v = tx[(size_t)i * DIM + d] / ls[d];
      As[(size_t)i * DIM + d] = v; s += v * v;
    }
    an[i] = s;
  } else if (i < N_TRAIN + N_TEST) {
    int j = i - N_TRAIN;
    float s = 0.f;
    #pragma unroll
    for (int d = 0; d < DIM; ++d) {
      float v = xx[(size_t)j * DIM + d] / ls[d];
      Bs[(size_t)j * DIM + d] = v; s += v * v;
    }
    bn[j] = s;
  }
}

// ---- kernel-matrix builder: thread owns column j (j-side coords in VGPRs),
//      i-side rows broadcast from LDS. Tile 128(i) x 256(j). ----
template <bool RHS>
__global__ __launch_bounds__(256) void build_kernel(
    const float* __restrict__ RI, const float* __restrict__ nI,  // i-side rows
    const float* __restrict__ RJ, const float* __restrict__ nJ,  // j-side (train)
    unsigned short* __restrict__ O1, unsigned short* __restrict__ O2,
    const float* __restrict__ osc, const float* __restrict__ noi)
{
  __shared__ float aI[128 * DIM];
  __shared__ float sI[128];
  int t = threadIdx.x;
  int j0 = blockIdx.x * 256, i0 = blockIdx.y * 128;
  for (int e = t; e < 128 * DIM; e += 256) aI[e] = RI[(size_t)i0 * DIM + e];
  if (t < 128) sI[t] = nI[i0 + t];
  __syncthreads();

  int j = j0 + t;
  f32x4 aj[4];
  const f32x4* RJ4 = (const f32x4*)(RJ + (size_t)j * DIM);
  #pragma unroll
  for (int q = 0; q < 4; ++q) aj[q] = RJ4[q];
  float nj = nJ[j];
  float s = osc[0], sn = noi[0];

  #pragma unroll 4
  for (int i = 0; i < 128; ++i) {
    float dot = 0.f;
    #pragma unroll
    for (int q = 0; q < 4; ++q) {
      f32x4 ai = *(const f32x4*)&aI[i * DIM + q * 4];
      dot += ai[0] * aj[q][0] + ai[1] * aj[q][1] + ai[2] * aj[q][2] + ai[3] * aj[q][3];
    }
    float d2 = fmaxf(sI[i] + nj - 2.f * dot, 0.f);
    float v = s * __expf(-0.5f * d2);
    if (!RHS && (i0 + i == j)) v += sn;
    unsigned short hv = f2bf(v);
    size_t idx = (size_t)(i0 + i) * KDIM + (size_t)j;
    O1[idx] = hv;
    if (RHS) O2[idx] = hv;
  }
}

// ---- bf16 MFMA GEMM:  Q[M][8192] = P[M][8192] * Khat^T (Khat row-major, symmetric)
//      template MF = A-fragments per wave; BM = MF*32 (tile BM x 128), waves 2x2 ----
template <int MF>
__global__ __launch_bounds__(256) void gemm_bt(
    const unsigned short* __restrict__ A,   // P [M][KDIM] bf16
    const unsigned short* __restrict__ B,   // Khat [8192][KDIM] bf16
    unsigned short* __restrict__ Cq)        // Q [M][8192] bf16
{
  constexpr int BM = MF * 32;
  __shared__ unsigned short Asm[BM * 64];
  __shared__ unsigned short Bsm[128 * 64];
  int tid = threadIdx.x;
  int lane = tid & 63, wave = tid >> 6;
  int wm = wave >> 1, wn = wave & 1;
  int bm = blockIdx.y * BM, bn = blockIdx.x * 128;

  const char* ga[MF]; const char* gb[4];
  char* la[MF]; char* lb[4];
  #pragma unroll
  for (int q = 0; q < MF; ++q) {
    int ob = q * 4096 + tid * 16;
    int r = ob >> 7, cb = ob & 127;            // 128 B per row (64 bf16)
    ga[q] = (const char*)(A + (size_t)(bm + r) * KDIM) + cb;
    la[q] = (char*)Asm + q * 4096 + wave * 1024;   // wave-uniform base
  }
  #pragma unroll
  for (int q = 0; q < 4; ++q) {
    int ob = q * 4096 + tid * 16;
    int r = ob >> 7, cb = ob & 127;
    gb[q] = (const char*)(B + (size_t)(bn + r) * KDIM) + cb;
    lb[q] = (char*)Bsm + q * 4096 + wave * 1024;
  }

  f32x4 acc[MF][4] = {};

  for (int kt = 0; kt < KDIM; kt += 64) {
    #pragma unroll
    for (int q = 0; q < MF; ++q) { gl_lds16(ga[q], la[q]); ga[q] += 128; }
    #pragma unroll
    for (int q = 0; q < 4; ++q)  { gl_lds16(gb[q], lb[q]); gb[q] += 128; }
    __syncthreads();
    #pragma unroll
    for (int ks = 0; ks < 2; ++ks) {
      int kc = ks * 32 + (lane >> 4) * 8;
      bf16x8 af[MF], bfr[4];
      #pragma unroll
      for (int i = 0; i < MF; ++i)
        af[i] = *(const bf16x8*)&Asm[(wm * (MF * 16) + i * 16 + (lane & 15)) * 64 + kc];
      #pragma unroll
      for (int jf = 0; jf < 4; ++jf)
        bfr[jf] = *(const bf16x8*)&Bsm[(wn * 64 + jf * 16 + (lane & 15)) * 64 + kc];
      #pragma unroll
      for (int i = 0; i < MF; ++i)
        #pragma unroll
        for (int jf = 0; jf < 4; ++jf)
          acc[i][jf] = __builtin_amdgcn_mfma_f32_16x16x32_bf16(af[i], bfr[jf], acc[i][jf], 0, 0, 0);
    }
    __syncthreads();
  }

  // verified C/D mapping: col = lane&15, row = (lane>>4)*4 + reg
  #pragma unroll
  for (int i = 0; i < MF; ++i) {
    #pragma unroll
    for (int jf = 0; jf < 4; ++jf) {
      int row = bm + wm * (MF * 16) + i * 16 + (lane >> 4) * 4;
      int col = bn + wn * 64 + jf * 16 + (lane & 15);
      #pragma unroll
      for (int rg = 0; rg < 4; ++rg)
        Cq[(size_t)(row + rg) * KDIM + col] = f2bf(acc[i][jf][rg]);
    }
  }
}

// ---- CG init: rr0 = ||b||^2, yp0 = y.b ; scal = {rr, yp, mean, bx} ----
__global__ __launch_bounds__(256) void cg_init(
    const unsigned short* __restrict__ R, const float* __restrict__ y,
    float* __restrict__ scal)
{
  __shared__ float sbuf[8];
  int c = blockIdx.x, t = threadIdx.x;
  size_t base = (size_t)c * KDIM;
  float rr = 0.f, yp = 0.f;
  #pragma unroll
  for (int k = 0; k < 4; ++k) {
    int j = k * 2048 + t * 8;
    bf16x8 r8 = *(const bf16x8*)&R[base + j];
    f32x4 y4a = *(const f32x4*)&y[j];
    f32x4 y4b = *(const f32x4*)&y[j + 4];
    #pragma unroll
    for (int e = 0; e < 8; ++e) {
      float v = bf2f((unsigned short)r8[e]);
      float yv = (e < 4) ? y4a[e] : y4b[e - 4];
      rr += v * v; yp += v * yv;
    }
  }
  block_reduce2(rr, yp, sbuf);
  if (t == 0) {
    scal[c * 4 + 0] = rr; scal[c * 4 + 1] = yp;
    scal[c * 4 + 2] = 0.f; scal[c * 4 + 3] = 0.f;
  }
}

// ---- one CG step (after Q = Khat * P); block per column ----
__global__ __launch_bounds__(256) void cg_step(
    const unsigned short* __restrict__ Q, unsigned short* __restrict__ R,
    unsigned short* __restrict__ P, const float* __restrict__ y,
    float* __restrict__ scal, const float* __restrict__ osc,
    const float* __restrict__ noi, float* __restrict__ out, int c0, int final_it)
{
  __shared__ float sbuf[8];
  int c = blockIdx.x, t = threadIdx.x;
  size_t base = (size_t)c * KDIM;

  // pass 1: pAp (keep q in regs)
  bf16x8 q8[4];
  float s1 = 0.f, zero = 0.f;
  #pragma unroll
  for (int k = 0; k < 4; ++k) {
    int j = k * 2048 + t * 8;
    q8[k] = *(const bf16x8*)&Q[base + j];
    bf16x8 p8 = *(const bf16x8*)&P[base + j];
    #pragma unroll
    for (int e = 0; e < 8; ++e)
      s1 += bf2f((unsigned short)p8[e]) * bf2f((unsigned short)q8[k][e]);
  }
  block_reduce2(s1, zero, sbuf);
  float rr   = scal[c * 4 + 0];
  float ypv  = scal[c * 4 + 1];
  float mean = scal[c * 4 + 2];
  float bx   = scal[c * 4 + 3];
  float alpha = rr / fmaxf(s1, 1e-30f);
  mean += alpha * ypv;
  bx   += alpha * rr;

  if (final_it) {
    if (t == 0) {
      out[c0 + c] = mean;
      out[N_TEST + c0 + c] = osc[0] + noi[0] - bx;
    }
    return;
  }

  // pass 2: r -= alpha*q ; rr_new, yr_new (on rounded values)
  float rnr[32];
  float s2 = 0.f, s3 = 0.f;
  #pragma unroll
  for (int k = 0; k < 4; ++k) {
    int j = k * 2048 + t * 8;
    bf16x8 r8 = *(const bf16x8*)&R[base + j];
    f32x4 y4a = *(const f32x4*)&y[j];
    f32x4 y4b = *(const f32x4*)&y[j + 4];
    bf16x8 w;
    #pragma unroll
    for (int e = 0; e < 8; ++e) {
      float rn = bf2f((unsigned short)r8[e]) - alpha * bf2f((unsigned short)q8[k][e]);
      unsigned short hb = f2bf(rn);
      float rq = bf2f(hb);
      w[e] = (short)hb;
      rnr[k * 8 + e] = rq;
      float yv = (e < 4) ? y4a[e] : y4b[e - 4];
      s2 += rq * rq; s3 += rq * yv;
    }
    *(bf16x8*)&R[base + j] = w;
  }
  block_reduce2(s2, s3, sbuf);
  float beta = s2 / fmaxf(rr, 1e-30f);
  float ypn  = s3 + beta * ypv;

  // pass 3: p = r_new + beta*p
  #pragma unroll
  for (int k = 0; k < 4; ++k) {
    int j = k * 2048 + t * 8;
    bf16x8 p8 = *(const bf16x8*)&P[base + j];
    bf16x8 w;
    #pragma unroll
    for (int e = 0; e < 8; ++e)
      w[e] = (short)f2bf(rnr[k * 8 + e] + beta * bf2f((unsigned short)p8[e]));
    *(bf16x8*)&P[base + j] = w;
  }
  if (t == 0) {
    scal[c * 4 + 0] = s2; scal[c * 4 + 1] = ypn;
    scal[c * 4 + 2] = mean; scal[c * 4 + 3] = bx;
  }
}

extern "C" void kernel_launch(void* const* d_in, const int* in_sizes, int n_in,
                              void* d_out, int out_size, void* d_ws, size_t ws_size,
                              hipStream_t stream) {
  const float* tx = (const float*)d_in[0];
  const float* ty = (const float*)d_in[1];
  const float* xx = (const float*)d_in[2];
  const float* os = (const float*)d_in[3];
  const float* ls = (const float*)d_in[4];
  const float* ns = (const float*)d_in[5];
  float* out = (float*)d_out;
  (void)in_sizes; (void)n_in; (void)out_size;

  auto pad = [](size_t x) { return (x + 255) & ~(size_t)255; };
  size_t fixed = pad((size_t)N_TRAIN * KDIM * 2)
               + pad((size_t)N_TRAIN * DIM * 4) + pad((size_t)N_TRAIN * 4)
               + pad((size_t)N_TEST * DIM * 4) + pad((size_t)N_TEST * 4);
  int C = 4096;
  while (C > 128) {
    size_t tot = fixed + 3 * pad((size_t)C * KDIM * 2) + pad((size_t)C * 16);
    if (tot <= ws_size) break;
    C >>= 1;
  }

  char* w = (char*)d_ws;
  auto alloc = [&](size_t bytes) { char* p = w; w += ((bytes + 255) & ~(size_t)255); return p; };
  unsigned short* Kb = (unsigned short*)alloc((size_t)N_TRAIN * KDIM * 2);
  float* As = (float*)alloc((size_t)N_TRAIN * DIM * 4);
  float* an = (float*)alloc((size_t)N_TRAIN * 4);
  float* Bs = (float*)alloc((size_t)N_TEST * DIM * 4);
  float* bn = (float*)alloc((size_t)N_TEST * 4);
  unsigned short* Rb = (unsigned short*)alloc((size_t)C * KDIM * 2);
  unsigned short* Pb = (unsigned short*)alloc((size_t)C * KDIM * 2);
  unsigned short* Qb = (unsigned short*)alloc((size_t)C * KDIM * 2);
  float* scal = (float*)alloc((size_t)C * 16);

  prep_kernel<<<48, 256, 0, stream>>>(tx, xx, ls, As, an, Bs, bn);

  build_kernel<false><<<dim3(KDIM / 256, N_TRAIN / 128), 256, 0, stream>>>(
      As, an, As, an, Kb, nullptr, os, ns);

  for (int c0 = 0; c0 < N_TEST; c0 += C) {
    build_kernel<true><<<dim3(KDIM / 256, C / 128), 256, 0, stream>>>(
        Bs + (size_t)c0 * DIM, bn + c0, As, an, Rb, Pb, os, ns);
    cg_init<<<C, 256, 0, stream>>>(Rb, ty, scal);
    for (int it = 0; it < CG_ITERS; ++it) {
      if (C >= 1024)
        gemm_bt<4><<<dim3(KDIM / 128, C / 128), 256, 0, stream>>>(Pb, Kb, Qb);
      else
        gemm_bt<2><<<dim3(KDIM / 128, C / 64), 256, 0, stream>>>(Pb, Kb, Qb);
      cg_step<<<C, 256, 0, stream>>>(Qb, Rb, Pb, ty, scal, os, ns, out, c0,
                                     it == CG_ITERS - 1 ? 1 : 0);
    }
  }
}

// Round 3
// 4434.594 us; speedup vs baseline: 3.7196x; 1.4065x over previous
//
#include <hip/hip_runtime.h>
#include <stdint.h>

// GP posterior via batched CG (scalar identities: mean = sum alpha*yp, b^Tx = sum alpha*rr).
// Khat bf16 (128 MB). CG matvec = bf16 MFMA GEMM with 8-phase-style counted-vmcnt
// pipeline (T2 swizzle + T3/T4 counted vmcnt(4) + T5 setprio + T1 XCD swizzle).

#define N_TRAIN 8192
#define N_TEST  4096
#define DIM     16
#define KDIM    8192
#define CG_ITERS 6
#define NT      (KDIM / 64)   // 128 K-tiles

using f32x4  = __attribute__((ext_vector_type(4))) float;
using bf16x8 = __attribute__((ext_vector_type(8))) short;

static __device__ __forceinline__ unsigned short f2bf(float f) {
  unsigned u = __float_as_uint(f);
  u = (u + 0x7FFFu + ((u >> 16) & 1u)) >> 16;   // RNE
  return (unsigned short)u;
}
static __device__ __forceinline__ float bf2f(unsigned short h) {
  return __uint_as_float(((unsigned)h) << 16);
}

__device__ __forceinline__ void gl_lds16(const void* g, void* l) {
  __builtin_amdgcn_global_load_lds(
      (const __attribute__((address_space(1))) unsigned int*)g,
      (__attribute__((address_space(3))) unsigned int*)l, 16, 0, 0);
}

__device__ __forceinline__ void block_reduce2(float& a, float& b, float* sbuf) {
  #pragma unroll
  for (int off = 32; off > 0; off >>= 1) {
    a += __shfl_down(a, off);
    b += __shfl_down(b, off);
  }
  int lane = threadIdx.x & 63, w = threadIdx.x >> 6;
  __syncthreads();
  if (lane == 0) { sbuf[w * 2] = a; sbuf[w * 2 + 1] = b; }
  __syncthreads();
  a = sbuf[0] + sbuf[2] + sbuf[4] + sbuf[6];
  b = sbuf[1] + sbuf[3] + sbuf[5] + sbuf[7];
}

// ---- prep: rows scaled by 1/lengthscale + squared norms ----
__global__ void prep_kernel(const float* __restrict__ tx, const float* __restrict__ xx,
                            const float* __restrict__ ls,
                            float* __restrict__ As, float* __restrict__ an,
                            float* __restrict__ Bs, float* __restrict__ bn) {
  int i = blockIdx.x * 256 + threadIdx.x;
  if (i < N_TRAIN) {
    float s = 0.f;
    #pragma unroll
    for (int d = 0; d < DIM; ++d) {
      float v = tx[(size_t)i * DIM + d] / ls[d];
      As[(size_t)i * DIM + d] = v; s += v * v;
    }
    an[i] = s;
  } else if (i < N_TRAIN + N_TEST) {
    int j = i - N_TRAIN;
    float s = 0.f;
    #pragma unroll
    for (int d = 0; d < DIM; ++d) {
      float v = xx[(size_t)j * DIM + d] / ls[d];
      Bs[(size_t)j * DIM + d] = v; s += v * v;
    }
    bn[j] = s;
  }
}

// ---- kernel-matrix builder (thread owns col j, rows broadcast from LDS) ----
template <bool RHS>
__global__ __launch_bounds__(256) void build_kernel(
    const float* __restrict__ RI, const float* __restrict__ nI,
    const float* __restrict__ RJ, const float* __restrict__ nJ,
    unsigned short* __restrict__ O1, unsigned short* __restrict__ O2,
    const float* __restrict__ osc, const float* __restrict__ noi)
{
  __shared__ float aI[128 * DIM];
  __shared__ float sI[128];
  int t = threadIdx.x;
  int j0 = blockIdx.x * 256, i0 = blockIdx.y * 128;
  for (int e = t; e < 128 * DIM; e += 256) aI[e] = RI[(size_t)i0 * DIM + e];
  if (t < 128) sI[t] = nI[i0 + t];
  __syncthreads();

  int j = j0 + t;
  f32x4 aj[4];
  const f32x4* RJ4 = (const f32x4*)(RJ + (size_t)j * DIM);
  #pragma unroll
  for (int q = 0; q < 4; ++q) aj[q] = RJ4[q];
  float nj = nJ[j];
  float s = osc[0], sn = noi[0];

  #pragma unroll 4
  for (int i = 0; i < 128; ++i) {
    float dot = 0.f;
    #pragma unroll
    for (int q = 0; q < 4; ++q) {
      f32x4 ai = *(const f32x4*)&aI[i * DIM + q * 4];
      dot += ai[0] * aj[q][0] + ai[1] * aj[q][1] + ai[2] * aj[q][2] + ai[3] * aj[q][3];
    }
    float d2 = fmaxf(sI[i] + nj - 2.f * dot, 0.f);
    float v = s * __expf(-0.5f * d2);
    if (!RHS && (i0 + i == j)) v += sn;
    unsigned short hv = f2bf(v);
    size_t idx = (size_t)(i0 + i) * KDIM + (size_t)j;
    O1[idx] = hv;
    if (RHS) O2[idx] = hv;
  }
}

// =====================  pipelined MFMA GEMM  =====================
// Q[M][8192] = P[M][8192] * Khat^T (Khat row-major, symmetric).
// Tile 128x128, BK=64, 4 waves (2x2), wave-output 64x64.
// LDS [2 dbuf][2 kk-half][128 rows x 32 bf16], XOR-swizzled rows.
// 4 phases/K-tile: stage 1 half (2 gl_lds) | ds_reads | bar | 8 MFMA | [vmcnt(4)] | bar

#define SWZ(x) ((x) ^ ((((x) >> 6) & 3) << 4))

__device__ __forceinline__ void stage_half(const char* grows, int kbyte,
                                           char* ldsbase, int tid, int wave) {
  #pragma unroll
  for (int q = 0; q < 2; ++q) {
    int off = q * 4096 + tid * 16;
    int loff = SWZ(off);
    int r = loff >> 6, c = loff & 63;
    gl_lds16(grows + (size_t)r * (KDIM * 2) + kbyte + c,
             ldsbase + q * 4096 + wave * 1024);   // wave-uniform dest
  }
}

__global__ __launch_bounds__(256) void gemm8p(
    const unsigned short* __restrict__ A,   // P [M][KDIM] bf16
    const unsigned short* __restrict__ Bm,  // Khat [8192][KDIM] bf16
    unsigned short* __restrict__ Cq,        // Q [M][8192] bf16
    int gy)                                  // M/128
{
  __shared__ char Ab[2][2][8192];   // 32 KB
  __shared__ char Bb[2][2][8192];   // 32 KB
  int tid = threadIdx.x, lane = tid & 63, wave = tid >> 6;
  int wm = wave >> 1, wn = wave & 1;

  // T1: XCD-chunked, column-major decomposition (chunk shares Khat panels)
  int nwg = gridDim.x;
  int orig = blockIdx.x;
  int wgid = (orig & 7) * (nwg >> 3) + (orig >> 3);
  int bx = wgid / gy, by = wgid % gy;

  const char* bA = (const char*)(A  + (size_t)(by * 128) * KDIM);
  const char* bB = (const char*)(Bm + (size_t)(bx * 128) * KDIM);

  // swizzled fragment byte-offsets (within an 8KB half)
  int aoff[4], boff[4];
  #pragma unroll
  for (int f = 0; f < 4; ++f) {
    int ab = (wm * 64 + f * 16 + (lane & 15)) * 64 + (lane >> 4) * 16;
    aoff[f] = SWZ(ab);
    int bb = (wn * 64 + f * 16 + (lane & 15)) * 64 + (lane >> 4) * 16;
    boff[f] = SWZ(bb);
  }

  f32x4 acc[4][4] = {};

#define LDA(p, kk, mf) (*(const bf16x8*)(&Ab[p][kk][0] + aoff[mf]))
#define LDB(p, kk, nf) (*(const bf16x8*)(&Bb[p][kk][0] + boff[nf]))
#define BAR() __builtin_amdgcn_s_barrier()
#define FENCE4() asm volatile("s_waitcnt vmcnt(4)" ::: "memory")
#define MFMA8(x, y, mb, B0, B1, B2, B3)                                          \
  acc[mb][0]   = __builtin_amdgcn_mfma_f32_16x16x32_bf16(x, B0, acc[mb][0],0,0,0);\
  acc[mb][1]   = __builtin_amdgcn_mfma_f32_16x16x32_bf16(x, B1, acc[mb][1],0,0,0);\
  acc[mb][2]   = __builtin_amdgcn_mfma_f32_16x16x32_bf16(x, B2, acc[mb][2],0,0,0);\
  acc[mb][3]   = __builtin_amdgcn_mfma_f32_16x16x32_bf16(x, B3, acc[mb][3],0,0,0);\
  acc[mb+1][0] = __builtin_amdgcn_mfma_f32_16x16x32_bf16(y, B0, acc[mb+1][0],0,0,0);\
  acc[mb+1][1] = __builtin_amdgcn_mfma_f32_16x16x32_bf16(y, B1, acc[mb+1][1],0,0,0);\
  acc[mb+1][2] = __builtin_amdgcn_mfma_f32_16x16x32_bf16(y, B2, acc[mb+1][2],0,0,0);\
  acc[mb+1][3] = __builtin_amdgcn_mfma_f32_16x16x32_bf16(y, B3, acc[mb+1][3],0,0,0);

  // prologue: stage tile 0 (kk0 then kk1), wait kk0, go
  stage_half(bB, 0,  &Bb[0][0][0], tid, wave);
  stage_half(bA, 0,  &Ab[0][0][0], tid, wave);
  stage_half(bB, 64, &Bb[0][1][0], tid, wave);
  stage_half(bA, 64, &Ab[0][1][0], tid, wave);
  FENCE4();
  BAR();

#define TILE(p, t)                                                              \
  {                                                                             \
    const bool st = (t) + 1 < NT;                                               \
    const int kb1 = ((t) + 1) * 128;                                            \
    /* ph0: kk0, mf01 */                                                        \
    if (st) stage_half(bB, kb1, &Bb[(p)^1][0][0], tid, wave);                   \
    bf16x8 b00 = LDB(p,0,0), b01 = LDB(p,0,1), b02 = LDB(p,0,2), b03 = LDB(p,0,3);\
    bf16x8 a00 = LDA(p,0,0), a01 = LDA(p,0,1);                                  \
    BAR();                                                                      \
    __builtin_amdgcn_s_setprio(1);                                              \
    MFMA8(a00, a01, 0, b00, b01, b02, b03);                                     \
    __builtin_amdgcn_s_setprio(0);                                              \
    BAR();                                                                      \
    /* ph1: kk0, mf23 */                                                        \
    if (st) stage_half(bA, kb1, &Ab[(p)^1][0][0], tid, wave);                   \
    bf16x8 a02 = LDA(p,0,2), a03 = LDA(p,0,3);                                  \
    BAR();                                                                      \
    __builtin_amdgcn_s_setprio(1);                                              \
    MFMA8(a02, a03, 2, b00, b01, b02, b03);                                     \
    __builtin_amdgcn_s_setprio(0);                                              \
    FENCE4();                                                                   \
    BAR();                                                                      \
    /* ph2: kk1, mf01 */                                                        \
    if (st) stage_half(bB, kb1 + 64, &Bb[(p)^1][1][0], tid, wave);              \
    bf16x8 b10 = LDB(p,1,0), b11 = LDB(p,1,1), b12 = LDB(p,1,2), b13 = LDB(p,1,3);\
    bf16x8 a10 = LDA(p,1,0), a11 = LDA(p,1,1);                                  \
    BAR();                                                                      \
    __builtin_amdgcn_s_setprio(1);                                              \
    MFMA8(a10, a11, 0, b10, b11, b12, b13);                                     \
    __builtin_amdgcn_s_setprio(0);                                              \
    BAR();                                                                      \
    /* ph3: kk1, mf23 */                                                        \
    if (st) stage_half(bA, kb1 + 64, &Ab[(p)^1][1][0], tid, wave);              \
    bf16x8 a12 = LDA(p,1,2), a13 = LDA(p,1,3);                                  \
    BAR();                                                                      \
    __builtin_amdgcn_s_setprio(1);                                              \
    MFMA8(a12, a13, 2, b10, b11, b12, b13);                                     \
    __builtin_amdgcn_s_setprio(0);                                              \
    FENCE4();                                                                   \
    BAR();                                                                      \
  }

  for (int t = 0; t < NT; t += 2) {
    TILE(0, t)
    TILE(1, t + 1)
  }

  // C/D mapping (verified): col = lane&15, row = (lane>>4)*4 + reg
  int bm = by * 128, bn = bx * 128;
  #pragma unroll
  for (int i = 0; i < 4; ++i) {
    #pragma unroll
    for (int jf = 0; jf < 4; ++jf) {
      int row = bm + wm * 64 + i * 16 + (lane >> 4) * 4;
      int col = bn + wn * 64 + jf * 16 + (lane & 15);
      #pragma unroll
      for (int rg = 0; rg < 4; ++rg)
        Cq[(size_t)(row + rg) * KDIM + col] = f2bf(acc[i][jf][rg]);
    }
  }
#undef TILE
#undef MFMA8
#undef FENCE4
#undef BAR
#undef LDA
#undef LDB
}

// ---- CG init: rr0 = ||b||^2, yp0 = y.b ; scal = {rr, yp, mean, bx} ----
__global__ __launch_bounds__(256) void cg_init(
    const unsigned short* __restrict__ R, const float* __restrict__ y,
    float* __restrict__ scal)
{
  __shared__ float sbuf[8];
  int c = blockIdx.x, t = threadIdx.x;
  size_t base = (size_t)c * KDIM;
  float rr = 0.f, yp = 0.f;
  #pragma unroll
  for (int k = 0; k < 4; ++k) {
    int j = k * 2048 + t * 8;
    bf16x8 r8 = *(const bf16x8*)&R[base + j];
    f32x4 y4a = *(const f32x4*)&y[j];
    f32x4 y4b = *(const f32x4*)&y[j + 4];
    #pragma unroll
    for (int e = 0; e < 8; ++e) {
      float v = bf2f((unsigned short)r8[e]);
      float yv = (e < 4) ? y4a[e] : y4b[e - 4];
      rr += v * v; yp += v * yv;
    }
  }
  block_reduce2(rr, yp, sbuf);
  if (t == 0) {
    scal[c * 4 + 0] = rr; scal[c * 4 + 1] = yp;
    scal[c * 4 + 2] = 0.f; scal[c * 4 + 3] = 0.f;
  }
}

// ---- one CG step (after Q = Khat * P); block per column ----
__global__ __launch_bounds__(256) void cg_step(
    const unsigned short* __restrict__ Q, unsigned short* __restrict__ R,
    unsigned short* __restrict__ P, const float* __restrict__ y,
    float* __restrict__ scal, const float* __restrict__ osc,
    const float* __restrict__ noi, float* __restrict__ out, int c0, int final_it)
{
  __shared__ float sbuf[8];
  int c = blockIdx.x, t = threadIdx.x;
  size_t base = (size_t)c * KDIM;

  bf16x8 q8[4];
  float s1 = 0.f, zero = 0.f;
  #pragma unroll
  for (int k = 0; k < 4; ++k) {
    int j = k * 2048 + t * 8;
    q8[k] = *(const bf16x8*)&Q[base + j];
    bf16x8 p8 = *(const bf16x8*)&P[base + j];
    #pragma unroll
    for (int e = 0; e < 8; ++e)
      s1 += bf2f((unsigned short)p8[e]) * bf2f((unsigned short)q8[k][e]);
  }
  block_reduce2(s1, zero, sbuf);
  float rr   = scal[c * 4 + 0];
  float ypv  = scal[c * 4 + 1];
  float mean = scal[c * 4 + 2];
  float bx   = scal[c * 4 + 3];
  float alpha = rr / fmaxf(s1, 1e-30f);
  mean += alpha * ypv;
  bx   += alpha * rr;

  if (final_it) {
    if (t == 0) {
      out[c0 + c] = mean;
      out[N_TEST + c0 + c] = osc[0] + noi[0] - bx;
    }
    return;
  }

  float rnr[32];
  float s2 = 0.f, s3 = 0.f;
  #pragma unroll
  for (int k = 0; k < 4; ++k) {
    int j = k * 2048 + t * 8;
    bf16x8 r8 = *(const bf16x8*)&R[base + j];
    f32x4 y4a = *(const f32x4*)&y[j];
    f32x4 y4b = *(const f32x4*)&y[j + 4];
    bf16x8 w;
    #pragma unroll
    for (int e = 0; e < 8; ++e) {
      float rn = bf2f((unsigned short)r8[e]) - alpha * bf2f((unsigned short)q8[k][e]);
      unsigned short hb = f2bf(rn);
      float rq = bf2f(hb);
      w[e] = (short)hb;
      rnr[k * 8 + e] = rq;
      float yv = (e < 4) ? y4a[e] : y4b[e - 4];
      s2 += rq * rq; s3 += rq * yv;
    }
    *(bf16x8*)&R[base + j] = w;
  }
  block_reduce2(s2, s3, sbuf);
  float beta = s2 / fmaxf(rr, 1e-30f);
  float ypn  = s3 + beta * ypv;

  #pragma unroll
  for (int k = 0; k < 4; ++k) {
    int j = k * 2048 + t * 8;
    bf16x8 p8 = *(const bf16x8*)&P[base + j];
    bf16x8 w;
    #pragma unroll
    for (int e = 0; e < 8; ++e)
      w[e] = (short)f2bf(rnr[k * 8 + e] + beta * bf2f((unsigned short)p8[e]));
    *(bf16x8*)&P[base + j] = w;
  }
  if (t == 0) {
    scal[c * 4 + 0] = s2; scal[c * 4 + 1] = ypn;
    scal[c * 4 + 2] = mean; scal[c * 4 + 3] = bx;
  }
}

extern "C" void kernel_launch(void* const* d_in, const int* in_sizes, int n_in,
                              void* d_out, int out_size, void* d_ws, size_t ws_size,
                              hipStream_t stream) {
  const float* tx = (const float*)d_in[0];
  const float* ty = (const float*)d_in[1];
  const float* xx = (const float*)d_in[2];
  const float* os = (const float*)d_in[3];
  const float* ls = (const float*)d_in[4];
  const float* ns = (const float*)d_in[5];
  float* out = (float*)d_out;
  (void)in_sizes; (void)n_in; (void)out_size;

  auto pad = [](size_t x) { return (x + 255) & ~(size_t)255; };
  size_t fixed = pad((size_t)N_TRAIN * KDIM * 2)
               + pad((size_t)N_TRAIN * DIM * 4) + pad((size_t)N_TRAIN * 4)
               + pad((size_t)N_TEST * DIM * 4) + pad((size_t)N_TEST * 4);
  int C = 4096;
  while (C > 128) {
    size_t tot = fixed + 3 * pad((size_t)C * KDIM * 2) + pad((size_t)C * 16);
    if (tot <= ws_size) break;
    C >>= 1;
  }

  char* w = (char*)d_ws;
  auto alloc = [&](size_t bytes) { char* p = w; w += ((bytes + 255) & ~(size_t)255); return p; };
  unsigned short* Kb = (unsigned short*)alloc((size_t)N_TRAIN * KDIM * 2);
  float* As = (float*)alloc((size_t)N_TRAIN * DIM * 4);
  float* an = (float*)alloc((size_t)N_TRAIN * 4);
  float* Bs = (float*)alloc((size_t)N_TEST * DIM * 4);
  float* bn = (float*)alloc((size_t)N_TEST * 4);
  unsigned short* Rb = (unsigned short*)alloc((size_t)C * KDIM * 2);
  unsigned short* Pb = (unsigned short*)alloc((size_t)C * KDIM * 2);
  unsigned short* Qb = (unsigned short*)alloc((size_t)C * KDIM * 2);
  float* scal = (float*)alloc((size_t)C * 16);

  prep_kernel<<<48, 256, 0, stream>>>(tx, xx, ls, As, an, Bs, bn);

  build_kernel<false><<<dim3(KDIM / 256, N_TRAIN / 128), 256, 0, stream>>>(
      As, an, As, an, Kb, nullptr, os, ns);

  for (int c0 = 0; c0 < N_TEST; c0 += C) {
    build_kernel<true><<<dim3(KDIM / 256, C / 128), 256, 0, stream>>>(
        Bs + (size_t)c0 * DIM, bn + c0, As, an, Rb, Pb, os, ns);
    cg_init<<<C, 256, 0, stream>>>(Rb, ty, scal);
    int gy = C / 128;
    for (int it = 0; it < CG_ITERS; ++it) {
      gemm8p<<<dim3(64 * gy), 256, 0, stream>>>(Pb, Kb, Qb, gy);
      cg_step<<<C, 256, 0, stream>>>(Qb, Rb, Pb, ty, scal, os, ns, out, c0,
                                     it == CG_ITERS - 1 ? 1 : 0);
    }
  }
}

// Round 4
// 4409.575 us; speedup vs baseline: 3.7407x; 1.0057x over previous
//
#include <hip/hip_runtime.h>
#include <stdint.h>

// GP posterior via batched CG (scalar identities: mean = sum alpha*yp, b^Tx = sum alpha*rr).
// Khat bf16 (128 MB). CG matvec = bf16 MFMA GEMM, 4-phase counted-vmcnt pipeline
// (T2 swizzle + T3/T4 + T5 setprio + T1 XCD swizzle) @ ~1.4 PF.
// cg_step: all loads issued up-front (no HBM burst behind a barrier), passes reg-only.

#define N_TRAIN 8192
#define N_TEST  4096
#define DIM     16
#define KDIM    8192
#define CG_ITERS 6
#define NT      (KDIM / 64)   // 128 K-tiles

using f32x4  = __attribute__((ext_vector_type(4))) float;
using bf16x8 = __attribute__((ext_vector_type(8))) short;

static __device__ __forceinline__ unsigned short f2bf(float f) {
  unsigned u = __float_as_uint(f);
  u = (u + 0x7FFFu + ((u >> 16) & 1u)) >> 16;   // RNE
  return (unsigned short)u;
}
static __device__ __forceinline__ float bf2f(unsigned short h) {
  return __uint_as_float(((unsigned)h) << 16);
}

__device__ __forceinline__ void gl_lds16(const void* g, void* l) {
  __builtin_amdgcn_global_load_lds(
      (const __attribute__((address_space(1))) unsigned int*)g,
      (__attribute__((address_space(3))) unsigned int*)l, 16, 0, 0);
}

__device__ __forceinline__ void block_reduce2(float& a, float& b, float* sbuf) {
  #pragma unroll
  for (int off = 32; off > 0; off >>= 1) {
    a += __shfl_down(a, off);
    b += __shfl_down(b, off);
  }
  int lane = threadIdx.x & 63, w = threadIdx.x >> 6;
  __syncthreads();
  if (lane == 0) { sbuf[w * 2] = a; sbuf[w * 2 + 1] = b; }
  __syncthreads();
  a = sbuf[0] + sbuf[2] + sbuf[4] + sbuf[6];
  b = sbuf[1] + sbuf[3] + sbuf[5] + sbuf[7];
}

// ---- prep: rows scaled by 1/lengthscale + squared norms ----
__global__ void prep_kernel(const float* __restrict__ tx, const float* __restrict__ xx,
                            const float* __restrict__ ls,
                            float* __restrict__ As, float* __restrict__ an,
                            float* __restrict__ Bs, float* __restrict__ bn) {
  int i = blockIdx.x * 256 + threadIdx.x;
  if (i < N_TRAIN) {
    float s = 0.f;
    #pragma unroll
    for (int d = 0; d < DIM; ++d) {
      float v = tx[(size_t)i * DIM + d] / ls[d];
      As[(size_t)i * DIM + d] = v; s += v * v;
    }
    an[i] = s;
  } else if (i < N_TRAIN + N_TEST) {
    int j = i - N_TRAIN;
    float s = 0.f;
    #pragma unroll
    for (int d = 0; d < DIM; ++d) {
      float v = xx[(size_t)j * DIM + d] / ls[d];
      Bs[(size_t)j * DIM + d] = v; s += v * v;
    }
    bn[j] = s;
  }
}

// ---- kernel-matrix builder: thread owns TWO columns (j, j+256); i-rows broadcast
//      from LDS so each ds_read_b128 feeds 2 columns' FMAs. Tile 128(i) x 512(j). ----
template <bool RHS>
__global__ __launch_bounds__(256) void build_kernel(
    const float* __restrict__ RI, const float* __restrict__ nI,
    const float* __restrict__ RJ, const float* __restrict__ nJ,
    unsigned short* __restrict__ O1, unsigned short* __restrict__ O2,
    const float* __restrict__ osc, const float* __restrict__ noi)
{
  __shared__ float aI[128 * DIM];
  __shared__ float sI[128];
  int t = threadIdx.x;
  int j0 = blockIdx.x * 512, i0 = blockIdx.y * 128;
  for (int e = t; e < 128 * DIM; e += 256) aI[e] = RI[(size_t)i0 * DIM + e];
  if (t < 128) sI[t] = nI[i0 + t];
  __syncthreads();

  int ja = j0 + t, jb = j0 + t + 256;
  f32x4 aj0[4], aj1[4];
  const f32x4* RJa = (const f32x4*)(RJ + (size_t)ja * DIM);
  const f32x4* RJb = (const f32x4*)(RJ + (size_t)jb * DIM);
  #pragma unroll
  for (int q = 0; q < 4; ++q) { aj0[q] = RJa[q]; aj1[q] = RJb[q]; }
  float nja = nJ[ja], njb = nJ[jb];
  float s = osc[0], sn = noi[0];

  #pragma unroll 4
  for (int i = 0; i < 128; ++i) {
    float d0 = 0.f, d1 = 0.f;
    #pragma unroll
    for (int q = 0; q < 4; ++q) {
      f32x4 ai = *(const f32x4*)&aI[i * DIM + q * 4];
      d0 += ai[0]*aj0[q][0] + ai[1]*aj0[q][1] + ai[2]*aj0[q][2] + ai[3]*aj0[q][3];
      d1 += ai[0]*aj1[q][0] + ai[1]*aj1[q][1] + ai[2]*aj1[q][2] + ai[3]*aj1[q][3];
    }
    float d2a = fmaxf(sI[i] + nja - 2.f * d0, 0.f);
    float d2b = fmaxf(sI[i] + njb - 2.f * d1, 0.f);
    float va = s * __expf(-0.5f * d2a);
    float vb = s * __expf(-0.5f * d2b);
    if (!RHS && (i0 + i == ja)) va += sn;
    if (!RHS && (i0 + i == jb)) vb += sn;
    unsigned short ha = f2bf(va), hb = f2bf(vb);
    size_t rowb = (size_t)(i0 + i) * KDIM;
    O1[rowb + ja] = ha; O1[rowb + jb] = hb;
    if (RHS) { O2[rowb + ja] = ha; O2[rowb + jb] = hb; }
  }
}

// =====================  pipelined MFMA GEMM (unchanged from r3)  =====================
#define SWZ(x) ((x) ^ ((((x) >> 6) & 3) << 4))

__device__ __forceinline__ void stage_half(const char* grows, int kbyte,
                                           char* ldsbase, int tid, int wave) {
  #pragma unroll
  for (int q = 0; q < 2; ++q) {
    int off = q * 4096 + tid * 16;
    int loff = SWZ(off);
    int r = loff >> 6, c = loff & 63;
    gl_lds16(grows + (size_t)r * (KDIM * 2) + kbyte + c,
             ldsbase + q * 4096 + wave * 1024);   // wave-uniform dest
  }
}

__global__ __launch_bounds__(256) void gemm8p(
    const unsigned short* __restrict__ A,   // P [M][KDIM] bf16
    const unsigned short* __restrict__ Bm,  // Khat [8192][KDIM] bf16
    unsigned short* __restrict__ Cq,        // Q [M][8192] bf16
    int gy)                                  // M/128
{
  __shared__ char Ab[2][2][8192];
  __shared__ char Bb[2][2][8192];
  int tid = threadIdx.x, lane = tid & 63, wave = tid >> 6;
  int wm = wave >> 1, wn = wave & 1;

  int nwg = gridDim.x;
  int orig = blockIdx.x;
  int wgid = (orig & 7) * (nwg >> 3) + (orig >> 3);
  int bx = wgid / gy, by = wgid % gy;

  const char* bA = (const char*)(A  + (size_t)(by * 128) * KDIM);
  const char* bB = (const char*)(Bm + (size_t)(bx * 128) * KDIM);

  int aoff[4], boff[4];
  #pragma unroll
  for (int f = 0; f < 4; ++f) {
    int ab = (wm * 64 + f * 16 + (lane & 15)) * 64 + (lane >> 4) * 16;
    aoff[f] = SWZ(ab);
    int bb = (wn * 64 + f * 16 + (lane & 15)) * 64 + (lane >> 4) * 16;
    boff[f] = SWZ(bb);
  }

  f32x4 acc[4][4] = {};

#define LDA(p, kk, mf) (*(const bf16x8*)(&Ab[p][kk][0] + aoff[mf]))
#define LDB(p, kk, nf) (*(const bf16x8*)(&Bb[p][kk][0] + boff[nf]))
#define BAR() __builtin_amdgcn_s_barrier()
#define FENCE4() asm volatile("s_waitcnt vmcnt(4)" ::: "memory")
#define MFMA8(x, y, mb, B0, B1, B2, B3)                                          \
  acc[mb][0]   = __builtin_amdgcn_mfma_f32_16x16x32_bf16(x, B0, acc[mb][0],0,0,0);\
  acc[mb][1]   = __builtin_amdgcn_mfma_f32_16x16x32_bf16(x, B1, acc[mb][1],0,0,0);\
  acc[mb][2]   = __builtin_amdgcn_mfma_f32_16x16x32_bf16(x, B2, acc[mb][2],0,0,0);\
  acc[mb][3]   = __builtin_amdgcn_mfma_f32_16x16x32_bf16(x, B3, acc[mb][3],0,0,0);\
  acc[mb+1][0] = __builtin_amdgcn_mfma_f32_16x16x32_bf16(y, B0, acc[mb+1][0],0,0,0);\
  acc[mb+1][1] = __builtin_amdgcn_mfma_f32_16x16x32_bf16(y, B1, acc[mb+1][1],0,0,0);\
  acc[mb+1][2] = __builtin_amdgcn_mfma_f32_16x16x32_bf16(y, B2, acc[mb+1][2],0,0,0);\
  acc[mb+1][3] = __builtin_amdgcn_mfma_f32_16x16x32_bf16(y, B3, acc[mb+1][3],0,0,0);

  stage_half(bB, 0,  &Bb[0][0][0], tid, wave);
  stage_half(bA, 0,  &Ab[0][0][0], tid, wave);
  stage_half(bB, 64, &Bb[0][1][0], tid, wave);
  stage_half(bA, 64, &Ab[0][1][0], tid, wave);
  FENCE4();
  BAR();

#define TILE(p, t)                                                              \
  {                                                                             \
    const bool st = (t) + 1 < NT;                                               \
    const int kb1 = ((t) + 1) * 128;                                            \
    if (st) stage_half(bB, kb1, &Bb[(p)^1][0][0], tid, wave);                   \
    bf16x8 b00 = LDB(p,0,0), b01 = LDB(p,0,1), b02 = LDB(p,0,2), b03 = LDB(p,0,3);\
    bf16x8 a00 = LDA(p,0,0), a01 = LDA(p,0,1);                                  \
    BAR();                                                                      \
    __builtin_amdgcn_s_setprio(1);                                              \
    MFMA8(a00, a01, 0, b00, b01, b02, b03);                                     \
    __builtin_amdgcn_s_setprio(0);                                              \
    BAR();                                                                      \
    if (st) stage_half(bA, kb1, &Ab[(p)^1][0][0], tid, wave);                   \
    bf16x8 a02 = LDA(p,0,2), a03 = LDA(p,0,3);                                  \
    BAR();                                                                      \
    __builtin_amdgcn_s_setprio(1);                                              \
    MFMA8(a02, a03, 2, b00, b01, b02, b03);                                     \
    __builtin_amdgcn_s_setprio(0);                                              \
    FENCE4();                                                                   \
    BAR();                                                                      \
    if (st) stage_half(bB, kb1 + 64, &Bb[(p)^1][1][0], tid, wave);              \
    bf16x8 b10 = LDB(p,1,0), b11 = LDB(p,1,1), b12 = LDB(p,1,2), b13 = LDB(p,1,3);\
    bf16x8 a10 = LDA(p,1,0), a11 = LDA(p,1,1);                                  \
    BAR();                                                                      \
    __builtin_amdgcn_s_setprio(1);                                              \
    MFMA8(a10, a11, 0, b10, b11, b12, b13);                                     \
    __builtin_amdgcn_s_setprio(0);                                              \
    BAR();                                                                      \
    if (st) stage_half(bA, kb1 + 64, &Ab[(p)^1][1][0], tid, wave);              \
    bf16x8 a12 = LDA(p,1,2), a13 = LDA(p,1,3);                                  \
    BAR();                                                                      \
    __builtin_amdgcn_s_setprio(1);                                              \
    MFMA8(a12, a13, 2, b10, b11, b12, b13);                                     \
    __builtin_amdgcn_s_setprio(0);                                              \
    FENCE4();                                                                   \
    BAR();                                                                      \
  }

  for (int t = 0; t < NT; t += 2) {
    TILE(0, t)
    TILE(1, t + 1)
  }

  int bm = by * 128, bn = bx * 128;
  #pragma unroll
  for (int i = 0; i < 4; ++i) {
    #pragma unroll
    for (int jf = 0; jf < 4; ++jf) {
      int row = bm + wm * 64 + i * 16 + (lane >> 4) * 4;
      int col = bn + wn * 64 + jf * 16 + (lane & 15);
      #pragma unroll
      for (int rg = 0; rg < 4; ++rg)
        Cq[(size_t)(row + rg) * KDIM + col] = f2bf(acc[i][jf][rg]);
    }
  }
#undef TILE
#undef MFMA8
#undef FENCE4
#undef BAR
#undef LDA
#undef LDB
}

// ---- CG init: rr0 = ||b||^2, yp0 = y.b ----
__global__ __launch_bounds__(256) void cg_init(
    const unsigned short* __restrict__ R, const float* __restrict__ y,
    float* __restrict__ scal)
{
  __shared__ float sbuf[8];
  int c = blockIdx.x, t = threadIdx.x;
  size_t base = (size_t)c * KDIM;
  bf16x8 r8[4];
  #pragma unroll
  for (int k = 0; k < 4; ++k) r8[k] = *(const bf16x8*)&R[base + k * 2048 + t * 8];
  float rr = 0.f, yp = 0.f;
  #pragma unroll
  for (int k = 0; k < 4; ++k) {
    int j = k * 2048 + t * 8;
    f32x4 y4a = *(const f32x4*)&y[j];
    f32x4 y4b = *(const f32x4*)&y[j + 4];
    #pragma unroll
    for (int e = 0; e < 8; ++e) {
      float v = bf2f((unsigned short)r8[k][e]);
      float yv = (e < 4) ? y4a[e] : y4b[e - 4];
      rr += v * v; yp += v * yv;
    }
  }
  block_reduce2(rr, yp, sbuf);
  if (t == 0) {
    scal[c * 4 + 0] = rr; scal[c * 4 + 1] = yp;
    scal[c * 4 + 2] = 0.f; scal[c * 4 + 3] = 0.f;
  }
}

// ---- one CG step: ALL loads issued before first reduce; passes register-only ----
__global__ __launch_bounds__(256) void cg_step(
    const unsigned short* __restrict__ Q, unsigned short* __restrict__ R,
    unsigned short* __restrict__ P, const float* __restrict__ y,
    float* __restrict__ scal, const float* __restrict__ osc,
    const float* __restrict__ noi, float* __restrict__ out, int c0, int final_it)
{
  __shared__ float sbuf[8];
  int c = blockIdx.x, t = threadIdx.x;
  size_t base = (size_t)c * KDIM;

  // burst: 8 (or 12) independent 16B loads in flight before any barrier
  bf16x8 q8[4], p8[4], r8[4];
  #pragma unroll
  for (int k = 0; k < 4; ++k) q8[k] = *(const bf16x8*)&Q[base + k * 2048 + t * 8];
  #pragma unroll
  for (int k = 0; k < 4; ++k) p8[k] = *(const bf16x8*)&P[base + k * 2048 + t * 8];
  if (!final_it) {
    #pragma unroll
    for (int k = 0; k < 4; ++k) r8[k] = *(const bf16x8*)&R[base + k * 2048 + t * 8];
  }

  float s1 = 0.f, zero = 0.f;
  #pragma unroll
  for (int k = 0; k < 4; ++k)
    #pragma unroll
    for (int e = 0; e < 8; ++e)
      s1 += bf2f((unsigned short)p8[k][e]) * bf2f((unsigned short)q8[k][e]);
  block_reduce2(s1, zero, sbuf);

  float rr   = scal[c * 4 + 0];
  float ypv  = scal[c * 4 + 1];
  float mean = scal[c * 4 + 2];
  float bx   = scal[c * 4 + 3];
  float alpha = rr / fmaxf(s1, 1e-30f);
  mean += alpha * ypv;
  bx   += alpha * rr;

  if (final_it) {
    if (t == 0) {
      out[c0 + c] = mean;
      out[N_TEST + c0 + c] = osc[0] + noi[0] - bx;
    }
    return;
  }

  // pass 2: r' = r - alpha*q (regs), write R, accumulate rr', y.r'
  float s2 = 0.f, s3 = 0.f;
  #pragma unroll
  for (int k = 0; k < 4; ++k) {
    int j = k * 2048 + t * 8;
    f32x4 y4a = *(const f32x4*)&y[j];
    f32x4 y4b = *(const f32x4*)&y[j + 4];
    bf16x8 w;
    #pragma unroll
    for (int e = 0; e < 8; ++e) {
      float rn = bf2f((unsigned short)r8[k][e]) - alpha * bf2f((unsigned short)q8[k][e]);
      unsigned short hb = f2bf(rn);
      float rq = bf2f(hb);
      w[e] = (short)hb;
      float yv = (e < 4) ? y4a[e] : y4b[e - 4];
      s2 += rq * rq; s3 += rq * yv;
    }
    r8[k] = w;                       // keep rounded r' for pass 3
    *(bf16x8*)&R[base + j] = w;
  }
  block_reduce2(s2, s3, sbuf);
  float beta = s2 / fmaxf(rr, 1e-30f);
  float ypn  = s3 + beta * ypv;

  // pass 3: p' = r' + beta*p (no loads)
  #pragma unroll
  for (int k = 0; k < 4; ++k) {
    int j = k * 2048 + t * 8;
    bf16x8 w;
    #pragma unroll
    for (int e = 0; e < 8; ++e)
      w[e] = (short)f2bf(bf2f((unsigned short)r8[k][e]) +
                         beta * bf2f((unsigned short)p8[k][e]));
    *(bf16x8*)&P[base + j] = w;
  }
  if (t == 0) {
    scal[c * 4 + 0] = s2; scal[c * 4 + 1] = ypn;
    scal[c * 4 + 2] = mean; scal[c * 4 + 3] = bx;
  }
}

extern "C" void kernel_launch(void* const* d_in, const int* in_sizes, int n_in,
                              void* d_out, int out_size, void* d_ws, size_t ws_size,
                              hipStream_t stream) {
  const float* tx = (const float*)d_in[0];
  const float* ty = (const float*)d_in[1];
  const float* xx = (const float*)d_in[2];
  const float* os = (const float*)d_in[3];
  const float* ls = (const float*)d_in[4];
  const float* ns = (const float*)d_in[5];
  float* out = (float*)d_out;
  (void)in_sizes; (void)n_in; (void)out_size;

  auto pad = [](size_t x) { return (x + 255) & ~(size_t)255; };
  size_t fixed = pad((size_t)N_TRAIN * KDIM * 2)
               + pad((size_t)N_TRAIN * DIM * 4) + pad((size_t)N_TRAIN * 4)
               + pad((size_t)N_TEST * DIM * 4) + pad((size_t)N_TEST * 4);
  int C = 4096;
  while (C > 128) {
    size_t tot = fixed + 3 * pad((size_t)C * KDIM * 2) + pad((size_t)C * 16);
    if (tot <= ws_size) break;
    C >>= 1;
  }

  char* w = (char*)d_ws;
  auto alloc = [&](size_t bytes) { char* p = w; w += ((bytes + 255) & ~(size_t)255); return p; };
  unsigned short* Kb = (unsigned short*)alloc((size_t)N_TRAIN * KDIM * 2);
  float* As = (float*)alloc((size_t)N_TRAIN * DIM * 4);
  float* an = (float*)alloc((size_t)N_TRAIN * 4);
  float* Bs = (float*)alloc((size_t)N_TEST * DIM * 4);
  float* bn = (float*)alloc((size_t)N_TEST * 4);
  unsigned short* Rb = (unsigned short*)alloc((size_t)C * KDIM * 2);
  unsigned short* Pb = (unsigned short*)alloc((size_t)C * KDIM * 2);
  unsigned short* Qb = (unsigned short*)alloc((size_t)C * KDIM * 2);
  float* scal = (float*)alloc((size_t)C * 16);

  prep_kernel<<<48, 256, 0, stream>>>(tx, xx, ls, As, an, Bs, bn);

  build_kernel<false><<<dim3(KDIM / 512, N_TRAIN / 128), 256, 0, stream>>>(
      As, an, As, an, Kb, nullptr, os, ns);

  for (int c0 = 0; c0 < N_TEST; c0 += C) {
    build_kernel<true><<<dim3(KDIM / 512, C / 128), 256, 0, stream>>>(
        Bs + (size_t)c0 * DIM, bn + c0, As, an, Rb, Pb, os, ns);
    cg_init<<<C, 256, 0, stream>>>(Rb, ty, scal);
    int gy = C / 128;
    for (int it = 0; it < CG_ITERS; ++it) {
      gemm8p<<<dim3(64 * gy), 256, 0, stream>>>(Pb, Kb, Qb, gy);
      cg_step<<<C, 256, 0, stream>>>(Qb, Rb, Pb, ty, scal, os, ns, out, c0,
                                     it == CG_ITERS - 1 ? 1 : 0);
    }
  }
}

// Round 5
// 3640.902 us; speedup vs baseline: 4.5304x; 1.2111x over previous
//
#include <hip/hip_runtime.h>
#include <stdint.h>

// GP posterior via batched CG. Khat bf16 (128 MB); matvec = 4-phase counted-vmcnt
// MFMA GEMM (~1.4 PF). CG scalars by recurrence: one reduction per step.
// it0 uses P=R=b (no cg_init, no P init); final iteration's pAp computed inside
// the gemm epilogue (atomics) -> no Q store, no final cg_step.

#define N_TRAIN 8192
#define N_TEST  4096
#define DIM     16
#define KDIM    8192
#define CG_ITERS 5
#define NT      (KDIM / 64)   // 128 K-tiles

using f32x4  = __attribute__((ext_vector_type(4))) float;
using bf16x8 = __attribute__((ext_vector_type(8))) short;

static __device__ __forceinline__ unsigned short f2bf(float f) {
  unsigned u = __float_as_uint(f);
  u = (u + 0x7FFFu + ((u >> 16) & 1u)) >> 16;   // RNE
  return (unsigned short)u;
}
static __device__ __forceinline__ float bf2f(unsigned short h) {
  return __uint_as_float(((unsigned)h) << 16);
}

__device__ __forceinline__ void gl_lds16(const void* g, void* l) {
  __builtin_amdgcn_global_load_lds(
      (const __attribute__((address_space(1))) unsigned int*)g,
      (__attribute__((address_space(3))) unsigned int*)l, 16, 0, 0);
}

__device__ __forceinline__ void block_reduce6(float* v, float* sbuf) {
  #pragma unroll
  for (int off = 32; off > 0; off >>= 1)
    #pragma unroll
    for (int i = 0; i < 6; ++i) v[i] += __shfl_down(v[i], off);
  int lane = threadIdx.x & 63, w = threadIdx.x >> 6;
  __syncthreads();
  if (lane == 0)
    #pragma unroll
    for (int i = 0; i < 6; ++i) sbuf[w * 6 + i] = v[i];
  __syncthreads();
  #pragma unroll
  for (int i = 0; i < 6; ++i)
    v[i] = sbuf[i] + sbuf[6 + i] + sbuf[12 + i] + sbuf[18 + i];
}

// ---- prep: rows scaled by 1/lengthscale + squared norms ----
__global__ void prep_kernel(const float* __restrict__ tx, const float* __restrict__ xx,
                            const float* __restrict__ ls,
                            float* __restrict__ As, float* __restrict__ an,
                            float* __restrict__ Bs, float* __restrict__ bn) {
  int i = blockIdx.x * 256 + threadIdx.x;
  if (i < N_TRAIN) {
    float s = 0.f;
    #pragma unroll
    for (int d = 0; d < DIM; ++d) {
      float v = tx[(size_t)i * DIM + d] / ls[d];
      As[(size_t)i * DIM + d] = v; s += v * v;
    }
    an[i] = s;
  } else if (i < N_TRAIN + N_TEST) {
    int j = i - N_TRAIN;
    float s = 0.f;
    #pragma unroll
    for (int d = 0; d < DIM; ++d) {
      float v = xx[(size_t)j * DIM + d] / ls[d];
      Bs[(size_t)j * DIM + d] = v; s += v * v;
    }
    bn[j] = s;
  }
}

// ---- kernel-matrix builder: thread owns 2 cols; i-rows broadcast from LDS ----
template <bool NOISE>
__global__ __launch_bounds__(256) void build_kernel(
    const float* __restrict__ RI, const float* __restrict__ nI,
    const float* __restrict__ RJ, const float* __restrict__ nJ,
    unsigned short* __restrict__ O1,
    const float* __restrict__ osc, const float* __restrict__ noi)
{
  __shared__ float aI[128 * DIM];
  __shared__ float sI[128];
  int t = threadIdx.x;
  int j0 = blockIdx.x * 512, i0 = blockIdx.y * 128;
  for (int e = t; e < 128 * DIM; e += 256) aI[e] = RI[(size_t)i0 * DIM + e];
  if (t < 128) sI[t] = nI[i0 + t];
  __syncthreads();

  int ja = j0 + t, jb = j0 + t + 256;
  f32x4 aj0[4], aj1[4];
  const f32x4* RJa = (const f32x4*)(RJ + (size_t)ja * DIM);
  const f32x4* RJb = (const f32x4*)(RJ + (size_t)jb * DIM);
  #pragma unroll
  for (int q = 0; q < 4; ++q) { aj0[q] = RJa[q]; aj1[q] = RJb[q]; }
  float nja = nJ[ja], njb = nJ[jb];
  float s = osc[0], sn = noi[0];

  #pragma unroll 4
  for (int i = 0; i < 128; ++i) {
    float d0 = 0.f, d1 = 0.f;
    #pragma unroll
    for (int q = 0; q < 4; ++q) {
      f32x4 ai = *(const f32x4*)&aI[i * DIM + q * 4];
      d0 += ai[0]*aj0[q][0] + ai[1]*aj0[q][1] + ai[2]*aj0[q][2] + ai[3]*aj0[q][3];
      d1 += ai[0]*aj1[q][0] + ai[1]*aj1[q][1] + ai[2]*aj1[q][2] + ai[3]*aj1[q][3];
    }
    float d2a = fmaxf(sI[i] + nja - 2.f * d0, 0.f);
    float d2b = fmaxf(sI[i] + njb - 2.f * d1, 0.f);
    float va = s * __expf(-0.5f * d2a);
    float vb = s * __expf(-0.5f * d2b);
    if (NOISE && (i0 + i == ja)) va += sn;
    if (NOISE && (i0 + i == jb)) vb += sn;
    size_t rowb = (size_t)(i0 + i) * KDIM;
    O1[rowb + ja] = f2bf(va); O1[rowb + jb] = f2bf(vb);
  }
}

// =====================  pipelined MFMA GEMM  =====================
#define SWZ(x) ((x) ^ ((((x) >> 6) & 3) << 4))

__device__ __forceinline__ void stage_half(const char* grows, int kbyte,
                                           char* ldsbase, int tid, int wave) {
  #pragma unroll
  for (int q = 0; q < 2; ++q) {
    int off = q * 4096 + tid * 16;
    int loff = SWZ(off);
    int r = loff >> 6, c = loff & 63;
    gl_lds16(grows + (size_t)r * (KDIM * 2) + kbyte + c,
             ldsbase + q * 4096 + wave * 1024);   // wave-uniform dest
  }
}

__global__ __launch_bounds__(256) void gemm8p(
    const unsigned short* __restrict__ A,   // P (or R for it0) [M][KDIM] bf16
    const unsigned short* __restrict__ Bm,  // Khat [8192][KDIM] bf16
    unsigned short* __restrict__ Cq,        // Q [M][8192] bf16
    int gy, int finalit, float* __restrict__ pq)
{
  __shared__ char Ab[2][2][8192];
  __shared__ char Bb[2][2][8192];
  int tid = threadIdx.x, lane = tid & 63, wave = tid >> 6;
  int wm = wave >> 1, wn = wave & 1;

  int nwg = gridDim.x;
  int orig = blockIdx.x;
  int wgid = (orig & 7) * (nwg >> 3) + (orig >> 3);
  int bx = wgid / gy, by = wgid % gy;

  const char* bA = (const char*)(A  + (size_t)(by * 128) * KDIM);
  const char* bB = (const char*)(Bm + (size_t)(bx * 128) * KDIM);

  int aoff[4], boff[4];
  #pragma unroll
  for (int f = 0; f < 4; ++f) {
    int ab = (wm * 64 + f * 16 + (lane & 15)) * 64 + (lane >> 4) * 16;
    aoff[f] = SWZ(ab);
    int bb = (wn * 64 + f * 16 + (lane & 15)) * 64 + (lane >> 4) * 16;
    boff[f] = SWZ(bb);
  }

  f32x4 acc[4][4] = {};

#define LDA(p, kk, mf) (*(const bf16x8*)(&Ab[p][kk][0] + aoff[mf]))
#define LDB(p, kk, nf) (*(const bf16x8*)(&Bb[p][kk][0] + boff[nf]))
#define BAR() __builtin_amdgcn_s_barrier()
#define FENCE4() asm volatile("s_waitcnt vmcnt(4)" ::: "memory")
#define MFMA8(x, y, mb, B0, B1, B2, B3)                                          \
  acc[mb][0]   = __builtin_amdgcn_mfma_f32_16x16x32_bf16(x, B0, acc[mb][0],0,0,0);\
  acc[mb][1]   = __builtin_amdgcn_mfma_f32_16x16x32_bf16(x, B1, acc[mb][1],0,0,0);\
  acc[mb][2]   = __builtin_amdgcn_mfma_f32_16x16x32_bf16(x, B2, acc[mb][2],0,0,0);\
  acc[mb][3]   = __builtin_amdgcn_mfma_f32_16x16x32_bf16(x, B3, acc[mb][3],0,0,0);\
  acc[mb+1][0] = __builtin_amdgcn_mfma_f32_16x16x32_bf16(y, B0, acc[mb+1][0],0,0,0);\
  acc[mb+1][1] = __builtin_amdgcn_mfma_f32_16x16x32_bf16(y, B1, acc[mb+1][1],0,0,0);\
  acc[mb+1][2] = __builtin_amdgcn_mfma_f32_16x16x32_bf16(y, B2, acc[mb+1][2],0,0,0);\
  acc[mb+1][3] = __builtin_amdgcn_mfma_f32_16x16x32_bf16(y, B3, acc[mb+1][3],0,0,0);

  stage_half(bB, 0,  &Bb[0][0][0], tid, wave);
  stage_half(bA, 0,  &Ab[0][0][0], tid, wave);
  stage_half(bB, 64, &Bb[0][1][0], tid, wave);
  stage_half(bA, 64, &Ab[0][1][0], tid, wave);
  FENCE4();
  BAR();

#define TILE(p, t)                                                              \
  {                                                                             \
    const bool st = (t) + 1 < NT;                                               \
    const int kb1 = ((t) + 1) * 128;                                            \
    if (st) stage_half(bB, kb1, &Bb[(p)^1][0][0], tid, wave);                   \
    bf16x8 b00 = LDB(p,0,0), b01 = LDB(p,0,1), b02 = LDB(p,0,2), b03 = LDB(p,0,3);\
    bf16x8 a00 = LDA(p,0,0), a01 = LDA(p,0,1);                                  \
    BAR();                                                                      \
    __builtin_amdgcn_s_setprio(1);                                              \
    MFMA8(a00, a01, 0, b00, b01, b02, b03);                                     \
    __builtin_amdgcn_s_setprio(0);                                              \
    BAR();                                                                      \
    if (st) stage_half(bA, kb1, &Ab[(p)^1][0][0], tid, wave);                   \
    bf16x8 a02 = LDA(p,0,2), a03 = LDA(p,0,3);                                  \
    BAR();                                                                      \
    __builtin_amdgcn_s_setprio(1);                                              \
    MFMA8(a02, a03, 2, b00, b01, b02, b03);                                     \
    __builtin_amdgcn_s_setprio(0);                                              \
    FENCE4();                                                                   \
    BAR();                                                                      \
    if (st) stage_half(bB, kb1 + 64, &Bb[(p)^1][1][0], tid, wave);              \
    bf16x8 b10 = LDB(p,1,0), b11 = LDB(p,1,1), b12 = LDB(p,1,2), b13 = LDB(p,1,3);\
    bf16x8 a10 = LDA(p,1,0), a11 = LDA(p,1,1);                                  \
    BAR();                                                                      \
    __builtin_amdgcn_s_setprio(1);                                              \
    MFMA8(a10, a11, 0, b10, b11, b12, b13);                                     \
    __builtin_amdgcn_s_setprio(0);                                              \
    BAR();                                                                      \
    if (st) stage_half(bA, kb1 + 64, &Ab[(p)^1][1][0], tid, wave);              \
    bf16x8 a12 = LDA(p,1,2), a13 = LDA(p,1,3);                                  \
    BAR();                                                                      \
    __builtin_amdgcn_s_setprio(1);                                              \
    MFMA8(a12, a13, 2, b10, b11, b12, b13);                                     \
    __builtin_amdgcn_s_setprio(0);                                              \
    FENCE4();                                                                   \
    BAR();                                                                      \
  }

  for (int t = 0; t < NT; t += 2) {
    TILE(0, t)
    TILE(1, t + 1)
  }

  int bm = by * 128, bn = bx * 128;
  if (!finalit) {
    // C/D mapping (verified): col = lane&15, row = (lane>>4)*4 + reg
    #pragma unroll
    for (int i = 0; i < 4; ++i) {
      #pragma unroll
      for (int jf = 0; jf < 4; ++jf) {
        int row = bm + wm * 64 + i * 16 + (lane >> 4) * 4;
        int col = bn + wn * 64 + jf * 16 + (lane & 15);
        #pragma unroll
        for (int rg = 0; rg < 4; ++rg)
          Cq[(size_t)(row + rg) * KDIM + col] = f2bf(acc[i][jf][rg]);
      }
    }
  } else {
    // final iteration: only pAp needed. pq[row] += sum_col P[row][col]*Q[row][col]
    #pragma unroll
    for (int i = 0; i < 4; ++i) {
      #pragma unroll
      for (int rg = 0; rg < 4; ++rg) {
        int row = bm + wm * 64 + i * 16 + (lane >> 4) * 4 + rg;
        float v = 0.f;
        #pragma unroll
        for (int jf = 0; jf < 4; ++jf) {
          int col = bn + wn * 64 + jf * 16 + (lane & 15);
          v += acc[i][jf][rg] * bf2f(A[(size_t)row * KDIM + col]);
        }
        v += __shfl_xor(v, 1); v += __shfl_xor(v, 2);
        v += __shfl_xor(v, 4); v += __shfl_xor(v, 8);
        if ((lane & 15) == 0) atomicAdd(&pq[row], v);
      }
    }
  }
#undef TILE
#undef MFMA8
#undef FENCE4
#undef BAR
#undef LDA
#undef LDB
}

// ---- CG step: one reduction pass (dots), one update pass.
//      scal[c*8]: {rr, yp, yr, mean, bx}.  FIRST: p=r=b, initializes scal. ----
template <bool FIRST>
__global__ __launch_bounds__(256) void cg_step(
    const unsigned short* __restrict__ Q, unsigned short* __restrict__ R,
    unsigned short* __restrict__ P, const float* __restrict__ y,
    float* __restrict__ scal, float* __restrict__ pq)
{
  __shared__ float sbuf[24];
  int c = blockIdx.x, t = threadIdx.x;
  size_t base = (size_t)c * KDIM;

  bf16x8 q8[4], r8[4], p8[4];
  #pragma unroll
  for (int k = 0; k < 4; ++k) q8[k] = *(const bf16x8*)&Q[base + k * 2048 + t * 8];
  #pragma unroll
  for (int k = 0; k < 4; ++k) r8[k] = *(const bf16x8*)&R[base + k * 2048 + t * 8];
  if (FIRST) {
    #pragma unroll
    for (int k = 0; k < 4; ++k) p8[k] = r8[k];
  } else {
    #pragma unroll
    for (int k = 0; k < 4; ++k) p8[k] = *(const bf16x8*)&P[base + k * 2048 + t * 8];
  }

  // dots: v = {pq, rq, qq, yq, rr, yr} (rr/yr only used on FIRST)
  float v[6] = {0.f, 0.f, 0.f, 0.f, 0.f, 0.f};
  #pragma unroll
  for (int k = 0; k < 4; ++k) {
    int j = k * 2048 + t * 8;
    f32x4 y4a = *(const f32x4*)&y[j];
    f32x4 y4b = *(const f32x4*)&y[j + 4];
    #pragma unroll
    for (int e = 0; e < 8; ++e) {
      float qv = bf2f((unsigned short)q8[k][e]);
      float rv = bf2f((unsigned short)r8[k][e]);
      float pv = FIRST ? rv : bf2f((unsigned short)p8[k][e]);
      float yv = (e < 4) ? y4a[e] : y4b[e - 4];
      v[0] += pv * qv; v[1] += rv * qv; v[2] += qv * qv; v[3] += yv * qv;
      if (FIRST) { v[4] += rv * rv; v[5] += yv * rv; }
    }
  }
  block_reduce6(v, sbuf);

  float rr, yp, yr, mean, bx;
  if (FIRST) {
    rr = v[4]; yp = v[5]; yr = v[5]; mean = 0.f; bx = 0.f;
  } else {
    rr = scal[c * 8 + 0]; yp = scal[c * 8 + 1]; yr = scal[c * 8 + 2];
    mean = scal[c * 8 + 3]; bx = scal[c * 8 + 4];
  }
  float alpha = rr / fmaxf(v[0], 1e-30f);
  mean += alpha * yp;
  bx   += alpha * rr;
  float rrn = fmaxf(rr - 2.f * alpha * v[1] + alpha * alpha * v[2], 0.f);
  float yrn = yr - alpha * v[3];
  float beta = rrn / fmaxf(rr, 1e-30f);
  float ypn  = yrn + beta * yp;

  // update: r' = r - alpha*q (write); p' = r' + beta*p (write)
  #pragma unroll
  for (int k = 0; k < 4; ++k) {
    int j = k * 2048 + t * 8;
    bf16x8 wr, wp;
    #pragma unroll
    for (int e = 0; e < 8; ++e) {
      float rn = bf2f((unsigned short)r8[k][e]) -
                 alpha * bf2f((unsigned short)q8[k][e]);
      unsigned short hb = f2bf(rn);
      float rq = bf2f(hb);
      wr[e] = (short)hb;
      float pv = FIRST ? bf2f((unsigned short)p8[k][e])
                       : bf2f((unsigned short)p8[k][e]);
      wp[e] = (short)f2bf(rq + beta * pv);
    }
    *(bf16x8*)&R[base + j] = wr;
    *(bf16x8*)&P[base + j] = wp;
  }
  if (t == 0) {
    scal[c * 8 + 0] = rrn; scal[c * 8 + 1] = ypn; scal[c * 8 + 2] = yrn;
    scal[c * 8 + 3] = mean; scal[c * 8 + 4] = bx;
    pq[c] = 0.f;   // zero for the final gemm's atomics (every step; last one counts)
  }
}

// ---- final outputs from pq (pAp of last iteration) + scal ----
__global__ void final_out(const float* __restrict__ pq, const float* __restrict__ scal,
                          const float* __restrict__ osc, const float* __restrict__ noi,
                          float* __restrict__ out, int c0, int C)
{
  int c = blockIdx.x * 256 + threadIdx.x;
  if (c >= C) return;
  float rr = scal[c * 8 + 0], yp = scal[c * 8 + 1];
  float mean = scal[c * 8 + 3], bx = scal[c * 8 + 4];
  float alpha = rr / fmaxf(pq[c], 1e-30f);
  mean += alpha * yp;
  bx   += alpha * rr;
  out[c0 + c] = mean;
  out[N_TEST + c0 + c] = osc[0] + noi[0] - bx;
}

extern "C" void kernel_launch(void* const* d_in, const int* in_sizes, int n_in,
                              void* d_out, int out_size, void* d_ws, size_t ws_size,
                              hipStream_t stream) {
  const float* tx = (const float*)d_in[0];
  const float* ty = (const float*)d_in[1];
  const float* xx = (const float*)d_in[2];
  const float* os = (const float*)d_in[3];
  const float* ls = (const float*)d_in[4];
  const float* ns = (const float*)d_in[5];
  float* out = (float*)d_out;
  (void)in_sizes; (void)n_in; (void)out_size;

  auto pad = [](size_t x) { return (x + 255) & ~(size_t)255; };
  size_t fixed = pad((size_t)N_TRAIN * KDIM * 2)
               + pad((size_t)N_TRAIN * DIM * 4) + pad((size_t)N_TRAIN * 4)
               + pad((size_t)N_TEST * DIM * 4) + pad((size_t)N_TEST * 4);
  int C = 4096;
  while (C > 128) {
    size_t tot = fixed + 3 * pad((size_t)C * KDIM * 2)
               + pad((size_t)C * 32) + pad((size_t)C * 4);
    if (tot <= ws_size) break;
    C >>= 1;
  }

  char* w = (char*)d_ws;
  auto alloc = [&](size_t bytes) { char* p = w; w += ((bytes + 255) & ~(size_t)255); return p; };
  unsigned short* Kb = (unsigned short*)alloc((size_t)N_TRAIN * KDIM * 2);
  float* As = (float*)alloc((size_t)N_TRAIN * DIM * 4);
  float* an = (float*)alloc((size_t)N_TRAIN * 4);
  float* Bs = (float*)alloc((size_t)N_TEST * DIM * 4);
  float* bn = (float*)alloc((size_t)N_TEST * 4);
  unsigned short* Rb = (unsigned short*)alloc((size_t)C * KDIM * 2);
  unsigned short* Pb = (unsigned short*)alloc((size_t)C * KDIM * 2);
  unsigned short* Qb = (unsigned short*)alloc((size_t)C * KDIM * 2);
  float* scal = (float*)alloc((size_t)C * 32);
  float* pq   = (float*)alloc((size_t)C * 4);

  prep_kernel<<<48, 256, 0, stream>>>(tx, xx, ls, As, an, Bs, bn);

  build_kernel<true><<<dim3(KDIM / 512, N_TRAIN / 128), 256, 0, stream>>>(
      As, an, As, an, Kb, os, ns);

  for (int c0 = 0; c0 < N_TEST; c0 += C) {
    build_kernel<false><<<dim3(KDIM / 512, C / 128), 256, 0, stream>>>(
        Bs + (size_t)c0 * DIM, bn + c0, As, an, Rb, os, ns);
    int gy = C / 128;
    for (int it = 0; it < CG_ITERS; ++it) {
      const unsigned short* Ain = (it == 0) ? Rb : Pb;
      int fin = (it == CG_ITERS - 1) ? 1 : 0;
      gemm8p<<<dim3(64 * gy), 256, 0, stream>>>(Ain, Kb, Qb, gy, fin, pq);
      if (!fin) {
        if (it == 0)
          cg_step<true><<<C, 256, 0, stream>>>(Qb, Rb, Pb, ty, scal, pq);
        else
          cg_step<false><<<C, 256, 0, stream>>>(Qb, Rb, Pb, ty, scal, pq);
      }
    }
    final_out<<<(C + 255) / 256, 256, 0, stream>>>(pq, scal, os, ns, out, c0, C);
  }
}